// Round 5
// baseline (273.380 us; speedup 1.0000x reference)
//
#include <hip/hip_runtime.h>
#include <hip/hip_bf16.h>

#define N_NODES 50000
#define N_EDGES 600000
#define D 128
#define NB_SCAN 196  // ceil(50000/256)

constexpr float AVG_D_LOG = 1.6094379124341003f;  // log(5)
constexpr float EPS_V = 1e-5f;

// ---- workspace byte offsets (total ~93.1 MB)
#define PQ_B     0ul           // bf16 [50000][256]  P|Q rows     = 25,600,000
#define AGG_B    25600000ul    // bf16 [50000][512]  mean|max|min|std = 51,200,000
#define HBF_B    76800000ul    // bf16 [50000][128]
#define WPRET2_B 89600000ul    // bf16 [256][128]   (P cols | Q cols, [n][k])
#define WPOSTT_B 89665536ul    // bf16 [128][1664]
#define WMIXT_B  90091520ul    // bf16 [128][128]
#define DEGC_B   90124288ul    // int  [50000]
#define OFF_B    90324288ul    // int  [50016]
#define CUR_B    90524352ul    // int  [50000]
#define SRCS_B   90724352ul    // int  [600000]  src ids in dst-sorted order
#define BSUM_B   93124352ul    // int  [256]

typedef __attribute__((ext_vector_type(8))) short bf16x8;
typedef __attribute__((ext_vector_type(4))) float f32x4;

__device__ __forceinline__ short f2b(float f) {
    unsigned u = __builtin_bit_cast(unsigned, f);
    u += 0x7fffu + ((u >> 16) & 1u);   // RNE
    return (short)(u >> 16);
}
__device__ __forceinline__ unsigned pk2(float a, float b) {
    return (unsigned)(unsigned short)f2b(a) | ((unsigned)(unsigned short)f2b(b) << 16);
}
__device__ __forceinline__ float blo(unsigned u) { return __uint_as_float(u << 16); }
__device__ __forceinline__ float bhi(unsigned u) { return __uint_as_float(u & 0xffff0000u); }

// async global->LDS, 16B per lane; LDS dest = wave-uniform base + lane*16
__device__ __forceinline__ void gld_lds16(const void* g, void* l) {
    __builtin_amdgcn_global_load_lds(
        (const __attribute__((address_space(1))) void*)g,
        (__attribute__((address_space(3))) void*)l, 16, 0, 0);
}

// counted-vmcnt barrier pair (T4)
#define WAIT_BAR(N) do {                                              \
    asm volatile("s_waitcnt vmcnt(" #N ")" ::: "memory");             \
    __builtin_amdgcn_sched_barrier(0);                                \
    __builtin_amdgcn_s_barrier();                                     \
    __builtin_amdgcn_sched_barrier(0);                                \
} while (0)
#define BAR_ONLY() do {                                               \
    __builtin_amdgcn_sched_barrier(0);                                \
    __builtin_amdgcn_s_barrier();                                     \
    __builtin_amdgcn_sched_barrier(0);                                \
} while (0)

// ---------------------------------------------------------------- prep (8-wide vectorized h conversion)
__global__ __launch_bounds__(256) void prep_kernel(
    const float* __restrict__ h, const float* __restrict__ Wpre,
    const float* __restrict__ Wpost, const float* __restrict__ Wmix,
    short* __restrict__ hbf, short* __restrict__ wpreT2,
    short* __restrict__ wpostT, short* __restrict__ wmixT,
    int* __restrict__ degc, int* __restrict__ cursor)
{
    long i = (long)blockIdx.x * 256 + threadIdx.x;
    if (i < 800000) {   // 6.4M elements, 8 per thread
        float4 a = *(const float4*)(h + i * 8);
        float4 b = *(const float4*)(h + i * 8 + 4);
        int4 v;
        v.x = (int)pk2(a.x, a.y); v.y = (int)pk2(a.z, a.w);
        v.z = (int)pk2(b.x, b.y); v.w = (int)pk2(b.z, b.w);
        *(int4*)(hbf + i * 8) = v;
        return;
    }
    i -= 800000;
    if (i < 32768) {  // wpreT2[n][k]: n<128 -> Wpre[k][n] (top); n>=128 -> Wpre[k+128][n-128]
        int n = i >> 7, k = i & 127;
        float v = (n < 128) ? Wpre[k * 128 + n] : Wpre[(k + 128) * 128 + (n - 128)];
        wpreT2[n * 128 + k] = f2b(v);
        return;
    }
    i -= 32768;
    if (i < 212992) { int k = i >> 7, n = i & 127; wpostT[n * 1664 + k] = f2b(Wpost[k * 128 + n]); return; }
    i -= 212992;
    if (i < 16384) { int k = i >> 7, n = i & 127; wmixT[n * 128 + k] = f2b(Wmix[k * 128 + n]); return; }
    i -= 16384;
    if (i < N_NODES) { degc[i] = 0; return; }
    i -= N_NODES;
    if (i < N_NODES) cursor[i] = 0;
}
#define PREP_BLOCKS ((800000 + 32768 + 212992 + 16384 + 2 * N_NODES + 255) / 256)

// ---------------------------------------------------------------- degree histogram
__global__ __launch_bounds__(256) void hist_kernel(const int* __restrict__ edst, int* __restrict__ degc) {
    int e = blockIdx.x * 256 + threadIdx.x;
    if (e < N_EDGES) atomicAdd(&degc[edst[e]], 1);
}

// ---------------------------------------------------------------- scan
__global__ __launch_bounds__(256) void scan1_kernel(const int* __restrict__ degc, int* __restrict__ bsum) {
    int n = blockIdx.x * 256 + threadIdx.x;
    int v = (n < N_NODES) ? degc[n] : 0;
#pragma unroll
    for (int o = 32; o > 0; o >>= 1) v += __shfl_down(v, o);
    __shared__ int w4[4];
    if ((threadIdx.x & 63) == 0) w4[threadIdx.x >> 6] = v;
    __syncthreads();
    if (threadIdx.x == 0) bsum[blockIdx.x] = w4[0] + w4[1] + w4[2] + w4[3];
}

__global__ __launch_bounds__(256) void scan2_kernel(int* __restrict__ bsum, int* __restrict__ off) {
    __shared__ int sd[256];
    int tid = threadIdx.x;
    int v = (tid < NB_SCAN) ? bsum[tid] : 0;
    sd[tid] = v;
    __syncthreads();
    for (int o = 1; o < 256; o <<= 1) {
        int t = (tid >= o) ? sd[tid - o] : 0;
        __syncthreads();
        sd[tid] += t;
        __syncthreads();
    }
    if (tid < NB_SCAN) bsum[tid] = sd[tid] - v;   // exclusive prefix
    if (tid == 0) off[N_NODES] = sd[255];
}

__global__ __launch_bounds__(256) void scan3_kernel(const int* __restrict__ degc,
                                                    const int* __restrict__ bsum, int* __restrict__ off) {
    __shared__ int sd[256];
    int tid = threadIdx.x;
    int n = blockIdx.x * 256 + tid;
    int v = (n < N_NODES) ? degc[n] : 0;
    sd[tid] = v;
    __syncthreads();
    for (int o = 1; o < 256; o <<= 1) {
        int t = (tid >= o) ? sd[tid - o] : 0;
        __syncthreads();
        sd[tid] += t;
        __syncthreads();
    }
    if (n < N_NODES) off[n] = sd[tid] - v + bsum[blockIdx.x];
}

// ---------------------------------------------------------------- scatter srcs into dst-sorted order
__global__ __launch_bounds__(256) void scatter_kernel(const int* __restrict__ esrc, const int* __restrict__ edst,
                                                      const int* __restrict__ off, int* __restrict__ cursor,
                                                      int* __restrict__ srcs) {
    int e = blockIdx.x * 256 + threadIdx.x;
    if (e < N_EDGES) {
        int d = edst[e];
        int p = off[d] + atomicAdd(&cursor[d], 1);
        srcs[p] = esrc[e];
    }
}

// ---------------------------------------------------------------- PQ = h @ [Wtop | Wbot] (+bias on Q)
__global__ __launch_bounds__(256) void gemm_pq_kernel(
    const short* __restrict__ hbf, const short* __restrict__ wpreT2,
    const float* __restrict__ bpre, short* __restrict__ PQ)
{
    __shared__ __align__(16) short As[128][72];
    __shared__ __align__(16) short Bs[128][72];

    const int tid = threadIdx.x;
    const int cg = blockIdx.x & 1;            // 0 = P cols, 1 = Q cols
    const int bn = (blockIdx.x >> 1) * 128;
    const int lane = tid & 63, wv = tid >> 6;
    const int lm = lane & 15, quad = lane >> 4;

    f32x4 acc[2][8];
#pragma unroll
    for (int a = 0; a < 2; a++)
#pragma unroll
        for (int b = 0; b < 8; b++) acc[a][b] = (f32x4){0.f, 0.f, 0.f, 0.f};

#pragma unroll
    for (int kc = 0; kc < 2; kc++) {
        __syncthreads();
#pragma unroll
        for (int t = 0; t < 4; t++) {
            int q = tid + t * 256;
            int m = q >> 3, seg = q & 7;
            int n = bn + m; if (n >= N_NODES) n = N_NODES - 1;
            *(int4*)&As[m][seg * 8] = *(const int4*)(hbf + (long)n * 128 + kc * 64 + seg * 8);
        }
#pragma unroll
        for (int t = 0; t < 4; t++) {
            int q = tid + t * 256;
            int n = q >> 3, seg = q & 7;
            *(int4*)&Bs[n][seg * 8] = *(const int4*)(wpreT2 + (cg * 128 + n) * 128 + kc * 64 + seg * 8);
        }
        __syncthreads();
#pragma unroll
        for (int ks = 0; ks < 2; ks++) {
            const int ko = ks * 32 + quad * 8;
            bf16x8 a0 = *(const bf16x8*)&As[wv * 32 + lm][ko];
            bf16x8 a1 = *(const bf16x8*)&As[wv * 32 + 16 + lm][ko];
#pragma unroll
            for (int ct = 0; ct < 8; ct++) {
                bf16x8 b = *(const bf16x8*)&Bs[ct * 16 + lm][ko];
                acc[0][ct] = __builtin_amdgcn_mfma_f32_16x16x32_bf16(b, a0, acc[0][ct], 0, 0, 0);
                acc[1][ct] = __builtin_amdgcn_mfma_f32_16x16x32_bf16(b, a1, acc[1][ct], 0, 0, 0);
            }
        }
    }

#pragma unroll
    for (int rt = 0; rt < 2; rt++) {
        int row = wv * 32 + rt * 16 + lm;
        int n = bn + row;
        if (n >= N_NODES) continue;
        short* dst = PQ + (long)n * 256;
#pragma unroll
        for (int ct = 0; ct < 8; ct++) {
            int col = cg * 128 + ct * 16 + quad * 4;
            float v0 = acc[rt][ct][0], v1 = acc[rt][ct][1], v2 = acc[rt][ct][2], v3 = acc[rt][ct][3];
            if (cg) {
                float4 bv = *(const float4*)(bpre + (col - 128));
                v0 += bv.x; v1 += bv.y; v2 += bv.z; v3 += bv.w;
            }
            int2 pkd; pkd.x = (int)pk2(v0, v1); pkd.y = (int)pk2(v2, v3);
            *(int2*)(dst + col) = pkd;
        }
    }
}

// ---------------------------------------------------------------- fused edge compute + stats: one wave per node
__global__ __launch_bounds__(256) void edgestats_kernel(
    const short* __restrict__ PQ, const int* __restrict__ srcs,
    const int* __restrict__ off, short* __restrict__ aggbf)
{
    const int wv = threadIdx.x >> 6, lane = threadIdx.x & 63;
    const int n = blockIdx.x * 4 + wv;            // grid 12500 * 4 waves = 50000
    const unsigned* Pb = (const unsigned*)PQ;     // u32 view: row = 128 u32 (P=0..63, Q=64..127)

    const int s0 = __builtin_amdgcn_readfirstlane(off[n]);
    const int s1 = __builtin_amdgcn_readfirstlane(off[n + 1]);

    unsigned qu = Pb[(long)n * 128 + 64 + lane];
    const float qa = blo(qu), qb = bhi(qu);

    float sA = 0.f, sB = 0.f, qA = 0.f, qB = 0.f;
    float mxA = -1e30f, mxB = -1e30f, mnA = 1e30f, mnB = 1e30f;

    int p = s0;
    for (; p + 8 <= s1; p += 8) {
        int idx[8];
#pragma unroll
        for (int j = 0; j < 8; j++) idx[j] = srcs[p + j];
        unsigned u[8];
#pragma unroll
        for (int j = 0; j < 8; j++) u[j] = Pb[(long)idx[j] * 128 + lane];
#pragma unroll
        for (int j = 0; j < 8; j++) {
            float a = blo(u[j]) + qa; a = a > 0.f ? a : 0.f;
            float b = bhi(u[j]) + qb; b = b > 0.f ? b : 0.f;
            sA += a; sB += b; qA += a * a; qB += b * b;
            mxA = fmaxf(mxA, a); mxB = fmaxf(mxB, b);
            mnA = fminf(mnA, a); mnB = fminf(mnB, b);
        }
    }
    for (; p < s1; p++) {
        unsigned u = Pb[(long)srcs[p] * 128 + lane];
        float a = blo(u) + qa; a = a > 0.f ? a : 0.f;
        float b = bhi(u) + qb; b = b > 0.f ? b : 0.f;
        sA += a; sB += b; qA += a * a; qB += b * b;
        mxA = fmaxf(mxA, a); mxB = fmaxf(mxB, b);
        mnA = fminf(mnA, a); mnB = fminf(mnB, b);
    }

    float inv = 1.0f / (float)(s1 - s0);   // deg >= 1 guaranteed (self-loops)
    float mA = sA * inv, mB = sB * inv;
    float vA = qA * inv - mA * mA; vA = vA > 0.f ? vA : 0.f;
    float vB = qB * inv - mB * mB; vB = vB > 0.f ? vB : 0.f;
    float stA = sqrtf(vA + EPS_V), stB = sqrtf(vB + EPS_V);

    unsigned* ag = (unsigned*)(aggbf + (long)n * 512);
    ag[lane]       = pk2(mA, mB);
    ag[64 + lane]  = pk2(mxA, mxB);
    ag[128 + lane] = pk2(mnA, mnB);
    ag[192 + lane] = pk2(stA, stB);
}

// ---------------------------------------------------------------- fused post + mix per node
// v6: LDS-traffic cut. Block = 2 waves (128 thr), wave = 32 rows x 128 cols.
// A (per-node data) loads DIRECT global->reg (read-once; staging it through LDS
// was pure LDS-pipe overhead: v5 ran 12 ds_read_b128 per 16 MFMA -> LDS-pipe-bound).
// Only B (shared weights) goes through LDS: 16 ds_read per 32 MFMA. Counted-vmcnt
// pipeline; T5 setprio around MFMA clusters; j-loop fully unrolled (static A regs).

// stage one 128x64 B tile: 8 gld_lds per wave (2 waves -> 16 KB)
__device__ __forceinline__ void stageB(short* ldsT, const short* src, int rs, int co,
                                       int wv, int lane) {
    const int sub = lane >> 3, seg = lane & 7;
    const int sg = (seg ^ sub) * 8;          // pre-swizzled global source
#pragma unroll
    for (int t = 0; t < 8; t++) {
        int i = wv * 8 + t;
        int row = i * 8 + sub;
        gld_lds16(src + (long)row * rs + co + sg, ldsT + i * 512);
    }
}

// load 4 A-fragments (rt x ks) for this wave's 32 rows, K=64 chunk at co (shorts)
__device__ __forceinline__ void loadA(bf16x8* a, const short* src, int rs, int co,
                                      int bn, int wv, int lm, int quad) {
#pragma unroll
    for (int rt = 0; rt < 2; rt++)
#pragma unroll
        for (int ks = 0; ks < 2; ks++) {
            int n = bn + wv * 32 + rt * 16 + lm; if (n >= N_NODES) n = N_NODES - 1;
            a[rt * 2 + ks] = *(const bf16x8*)(src + (long)n * rs + co + ks * 32 + quad * 8);
        }
}

// id-group: mI += A x B   (16 ds_read, 32 MFMA)
#define GROUP_ID(BB, AF)                                                            \
    {                                                                               \
        __builtin_amdgcn_s_setprio(1);                                              \
        _Pragma("unroll")                                                           \
        for (int ks = 0; ks < 2; ks++) {                                            \
            const int qx = ((ks * 4 + quad) ^ r7) * 8;                              \
            _Pragma("unroll")                                                       \
            for (int ct = 0; ct < 8; ct++) {                                        \
                bf16x8 b = *(const bf16x8*)&(BB)[(ct * 16 + lm) * 64 + qx];         \
                mI[0][ct] = __builtin_amdgcn_mfma_f32_16x16x32_bf16(b, (AF)[ks], mI[0][ct], 0, 0, 0); \
                mI[1][ct] = __builtin_amdgcn_mfma_f32_16x16x32_bf16(b, (AF)[2 + ks], mI[1][ct], 0, 0, 0); \
            }                                                                       \
        }                                                                           \
        __builtin_amdgcn_s_setprio(0);                                              \
    }

// scaled group: mI += S * (A x B), via ct-half temp (32 regs) + VALU fold
#define GROUP_SC(BB, AF, S0, S1)                                                    \
    {                                                                               \
        _Pragma("unroll")                                                           \
        for (int ch = 0; ch < 2; ch++) {                                            \
            f32x4 tp[2][4];                                                         \
            __builtin_amdgcn_s_setprio(1);                                          \
            _Pragma("unroll")                                                       \
            for (int ks = 0; ks < 2; ks++) {                                        \
                const int qx = ((ks * 4 + quad) ^ r7) * 8;                          \
                _Pragma("unroll")                                                   \
                for (int c = 0; c < 4; c++) {                                       \
                    bf16x8 b = *(const bf16x8*)&(BB)[((ch * 4 + c) * 16 + lm) * 64 + qx]; \
                    f32x4 c0 = ks ? tp[0][c] : (f32x4){0.f, 0.f, 0.f, 0.f};         \
                    f32x4 c1 = ks ? tp[1][c] : (f32x4){0.f, 0.f, 0.f, 0.f};         \
                    tp[0][c] = __builtin_amdgcn_mfma_f32_16x16x32_bf16(b, (AF)[ks], c0, 0, 0, 0); \
                    tp[1][c] = __builtin_amdgcn_mfma_f32_16x16x32_bf16(b, (AF)[2 + ks], c1, 0, 0, 0); \
                }                                                                   \
            }                                                                       \
            __builtin_amdgcn_s_setprio(0);                                          \
            _Pragma("unroll")                                                       \
            for (int c = 0; c < 4; c++) {                                           \
                mI[0][ch * 4 + c] += (S0) * tp[0][c];                               \
                mI[1][ch * 4 + c] += (S1) * tp[1][c];                               \
            }                                                                       \
        }                                                                           \
    }

__global__ __launch_bounds__(128, 2) void node_kernel(
    const float* __restrict__ h, const short* __restrict__ hbf, const short* __restrict__ aggbf,
    const int* __restrict__ degc, const short* __restrict__ wpostT, const float* __restrict__ bpost,
    const short* __restrict__ wmixT, const float* __restrict__ bmix, float* __restrict__ out)
{
    __shared__ __align__(16) short Bs[2][8192];   // 2 x (128 rows x 64 shorts) = 32 KB
    __shared__ __align__(16) short AsH[2][4096];  // hp staging: 2 x (64 rows x 64 shorts) = 16 KB
    __shared__ float sAmp[64], sAtt[64];

    const int tid = threadIdx.x;
    const int bn = blockIdx.x * 64;
    const int lane = tid & 63, wv = tid >> 6;     // 2 waves: rows wv*32..
    const int lm = lane & 15, quad = lane >> 4;
    const int r7 = lm & 7;

    if (tid < 64) {
        int n = bn + tid; if (n >= N_NODES) n = N_NODES - 1;
        float d = (float)degc[n];
        float ld = logf(d + 1.0f);
        sAmp[tid] = ld * (1.0f / AVG_D_LOG);
        sAtt[tid] = AVG_D_LOG / ld;
    }
    __syncthreads();   // vmcnt baseline 0 + sAmp visible

    const float am0 = sAmp[wv * 32 + lm],      at0 = sAtt[wv * 32 + lm];
    const float am1 = sAmp[wv * 32 + 16 + lm], at1 = sAtt[wv * 32 + 16 + lm];

    f32x4 mI[2][8];
    bf16x8 aF[2][4];   // A-frag double buffer (static after full unroll)

    // prologue: A h0 -> aF[0] (4), A h1 -> aF[1] (4), B c0 -> Bs[0] (8)   [16 out]
    loadA(aF[0], hbf, 128, 0, bn, wv, lm, quad);
    loadA(aF[1], hbf, 128, 64, bn, wv, lm, quad);
    stageB(Bs[0], wpostT, 1664, 0, wv, lane);

    // p0: issue B c1 (8); wait prologue; compute h0 x c0 -> mI (fresh via explicit zero)
#pragma unroll
    for (int a = 0; a < 2; a++)
#pragma unroll
        for (int b = 0; b < 8; b++) mI[a][b] = (f32x4){0.f, 0.f, 0.f, 0.f};
    stageB(Bs[1], wpostT, 1664, 64, wv, lane);
    WAIT_BAR(8);
    GROUP_ID(Bs[0], aF[0]);
    BAR_ONLY();

    // p1: issue B id0 (8) + A agg0 -> aF[0] (4); wait p0's 8; compute h1 x c1
    stageB(Bs[0], wpostT, 1664, 2 * 64, wv, lane);
    loadA(aF[0], aggbf, 512, 0, bn, wv, lm, quad);
    WAIT_BAR(12);
    GROUP_ID(Bs[1], aF[1]);
    BAR_ONLY();

#pragma unroll
    for (int j = 0; j < 8; j++) {
        const int pb = j & 1;           // Bs parity holding id_j; A in aF[j&1]
        // s0 (id_j from Bs[pb] -> mI): issue Bamp_j
        stageB(Bs[pb ^ 1], wpostT, 1664, (10 + j) * 64, wv, lane);
        WAIT_BAR(8);
        GROUP_ID(Bs[pb], aF[j & 1]);
        BAR_ONLY();

        // s1 (amp_j from Bs[pb^1] -> fold): issue Batt_j
        stageB(Bs[pb], wpostT, 1664, (18 + j) * 64, wv, lane);
        WAIT_BAR(8);
        GROUP_SC(Bs[pb ^ 1], aF[j & 1], am0, am1);
        BAR_ONLY();

        // s2 (att_j from Bs[pb] -> fold): issue Bid_{j+1}+Aagg_{j+1} (or mixB0 at j=7)
        if (j < 7) {
            stageB(Bs[pb ^ 1], wpostT, 1664, (3 + j) * 64, wv, lane);
            loadA(aF[(j + 1) & 1], aggbf, 512, ((j + 1) >> 1) * 128 + ((j + 1) & 1) * 64, bn, wv, lm, quad);
            WAIT_BAR(12);
        } else {
            stageB(Bs[pb ^ 1], wmixT, 128, 0, wv, lane);   // mix kc=0 -> Bs[0]
            WAIT_BAR(8);
        }
        GROUP_SC(Bs[pb], aF[j & 1], at0, at1);
        BAR_ONLY();
    }
    // mix0 in flight -> Bs[0]

    // combine: issue mix1 -> Bs[1]; hp = relu(mI + bpost); pack swizzled -> AsH
    stageB(Bs[1], wmixT, 128, 64, wv, lane);
#pragma unroll
    for (int rt = 0; rt < 2; rt++) {
        const int row = wv * 32 + rt * 16 + lm;
#pragma unroll
        for (int ct = 0; ct < 8; ct++) {
            float4 bv = *(const float4*)(bpost + ct * 16 + quad * 4);
            float v0 = mI[rt][ct][0] + bv.x; v0 = v0 > 0.f ? v0 : 0.f;
            float v1 = mI[rt][ct][1] + bv.y; v1 = v1 > 0.f ? v1 : 0.f;
            float v2 = mI[rt][ct][2] + bv.z; v2 = v2 > 0.f ? v2 : 0.f;
            float v3 = mI[rt][ct][3] + bv.w; v3 = v3 > 0.f ? v3 : 0.f;
            int2 pkd; pkd.x = (int)pk2(v0, v1); pkd.y = (int)pk2(v2, v3);
            const int cb = (ct & 3) * 32 + quad * 8;           // byte off within 128B row
            const int sb = ((((cb >> 4) ^ r7) << 4) | (cb & 15));
            *(int2*)((char*)AsH[ct >> 2] + row * 128 + sb) = pkd;
        }
    }
    __syncthreads();   // full drain: mix loads (vmcnt) + hp writes (lgkm)

    // ---- mix GEMM: K=128, hp A-frags from AsH, Wmix B-frags from Bs
    f32x4 accO[2][8];
#pragma unroll
    for (int kc = 0; kc < 2; kc++) {
#pragma unroll
        for (int ks = 0; ks < 2; ks++) {
            const int qx = ((ks * 4 + quad) ^ r7) * 8;
            bf16x8 a0 = *(const bf16x8*)&AsH[kc][(wv * 32 + lm) * 64 + qx];
            bf16x8 a1 = *(const bf16x8*)&AsH[kc][(wv * 32 + 16 + lm) * 64 + qx];
#pragma unroll
            for (int ct = 0; ct < 8; ct++) {
                bf16x8 b = *(const bf16x8*)&Bs[kc][(ct * 16 + lm) * 64 + qx];
                f32x4 c0 = (kc == 0 && ks == 0) ? (f32x4){0.f, 0.f, 0.f, 0.f} : accO[0][ct];
                f32x4 c1 = (kc == 0 && ks == 0) ? (f32x4){0.f, 0.f, 0.f, 0.f} : accO[1][ct];
                accO[0][ct] = __builtin_amdgcn_mfma_f32_16x16x32_bf16(b, a0, c0, 0, 0, 0);
                accO[1][ct] = __builtin_amdgcn_mfma_f32_16x16x32_bf16(b, a1, c1, 0, 0, 0);
            }
        }
    }

    // epilogue: out = h + leaky_relu(accO + b_mix)
#pragma unroll
    for (int rt = 0; rt < 2; rt++) {
        int row = wv * 32 + rt * 16 + lm;
        int n = bn + row;
        if (n >= N_NODES) continue;
#pragma unroll
        for (int ct = 0; ct < 8; ct++) {
            int col = ct * 16 + quad * 4;
            float4 bv = *(const float4*)(bmix + col);
            float4 hv = *(const float4*)(h + (long)n * 128 + col);
            float4 o;
            float v0 = accO[rt][ct][0] + bv.x; v0 = v0 > 0.f ? v0 : 0.01f * v0; o.x = hv.x + v0;
            float v1 = accO[rt][ct][1] + bv.y; v1 = v1 > 0.f ? v1 : 0.01f * v1; o.y = hv.y + v1;
            float v2 = accO[rt][ct][2] + bv.z; v2 = v2 > 0.f ? v2 : 0.01f * v2; o.z = hv.z + v2;
            float v3 = accO[rt][ct][3] + bv.w; v3 = v3 > 0.f ? v3 : 0.01f * v3; o.w = hv.w + v3;
            *(float4*)(out + (long)n * 128 + col) = o;
        }
    }
}

extern "C" void kernel_launch(void* const* d_in, const int* in_sizes, int n_in,
                              void* d_out, int out_size, void* d_ws, size_t ws_size,
                              hipStream_t stream) {
    const float* h     = (const float*)d_in[0];
    const int*   esrc  = (const int*)d_in[1];
    const int*   edst  = (const int*)d_in[2];
    const float* Wpre  = (const float*)d_in[3];
    const float* bpre  = (const float*)d_in[4];
    const float* Wpost = (const float*)d_in[5];
    const float* bpost = (const float*)d_in[6];
    const float* Wmix  = (const float*)d_in[7];
    const float* bmix  = (const float*)d_in[8];
    float* out = (float*)d_out;
    char* ws = (char*)d_ws;

    short* PQ     = (short*)(ws + PQ_B);
    short* aggbf  = (short*)(ws + AGG_B);
    short* hbf    = (short*)(ws + HBF_B);
    short* wpreT2 = (short*)(ws + WPRET2_B);
    short* wpostT = (short*)(ws + WPOSTT_B);
    short* wmixT  = (short*)(ws + WMIXT_B);
    int*   degc   = (int*)(ws + DEGC_B);
    int*   off    = (int*)(ws + OFF_B);
    int*   cursor = (int*)(ws + CUR_B);
    int*   srcs   = (int*)(ws + SRCS_B);
    int*   bsum   = (int*)(ws + BSUM_B);

    prep_kernel<<<PREP_BLOCKS, 256, 0, stream>>>(h, Wpre, Wpost, Wmix, hbf, wpreT2, wpostT, wmixT, degc, cursor);
    hist_kernel<<<(N_EDGES + 255) / 256, 256, 0, stream>>>(edst, degc);
    scan1_kernel<<<NB_SCAN, 256, 0, stream>>>(degc, bsum);
    scan2_kernel<<<1, 256, 0, stream>>>(bsum, off);
    scan3_kernel<<<NB_SCAN, 256, 0, stream>>>(degc, bsum, off);
    scatter_kernel<<<(N_EDGES + 255) / 256, 256, 0, stream>>>(esrc, edst, off, cursor, srcs);
    gemm_pq_kernel<<<((N_NODES + 127) / 128) * 2, 256, 0, stream>>>(hbf, wpreT2, bpre, PQ);
    edgestats_kernel<<<N_NODES / 4, 256, 0, stream>>>(PQ, srcs, off, aggbf);
    node_kernel<<<(N_NODES + 63) / 64, 128, 0, stream>>>(h, hbf, aggbf, degc, wpostT, bpost, wmixT, bmix, out);
}

// Round 7
// 254.525 us; speedup vs baseline: 1.0741x; 1.0741x over previous
//
#include <hip/hip_runtime.h>
#include <hip/hip_bf16.h>

#define N_NODES 50000
#define N_EDGES 600000
#define D 128

constexpr float AVG_D_LOG = 1.6094379124341003f;  // log(5)
constexpr float EPS_V = 1e-5f;

// ---- workspace byte offsets (total ~93.1 MB)
#define PQ_B     0ul           // bf16 [50000][256]  P|Q rows     = 25,600,000
#define AGG_B    25600000ul    // bf16 [50000][512]  mean|max|min|std = 51,200,000
#define HBF_B    76800000ul    // bf16 [50000][128]
#define WPRET2_B 89600000ul    // bf16 [256][128]   (P cols | Q cols, [n][k])
#define WPOSTT_B 89665536ul    // bf16 [128][1664]
#define WMIXT_B  90091520ul    // bf16 [128][128]
#define DEGC_B   90124288ul    // int  [50000]
#define OFF_B    90324288ul    // int  [50016]
#define CUR_B    90524352ul    // int  [50000]
#define SRCS_B   90724352ul    // int  [600000]  src ids in dst-sorted order
#define GCNT_B   93124352ul    // int  [1]  global range allocator

typedef __attribute__((ext_vector_type(8))) short bf16x8;
typedef __attribute__((ext_vector_type(4))) float f32x4;

__device__ __forceinline__ short f2b(float f) {
    unsigned u = __builtin_bit_cast(unsigned, f);
    u += 0x7fffu + ((u >> 16) & 1u);   // RNE
    return (short)(u >> 16);
}
__device__ __forceinline__ unsigned pk2(float a, float b) {
    return (unsigned)(unsigned short)f2b(a) | ((unsigned)(unsigned short)f2b(b) << 16);
}
__device__ __forceinline__ float blo(unsigned u) { return __uint_as_float(u << 16); }
__device__ __forceinline__ float bhi(unsigned u) { return __uint_as_float(u & 0xffff0000u); }

// async global->LDS, 16B per lane; LDS dest = wave-uniform base + lane*16
__device__ __forceinline__ void gld_lds16(const void* g, void* l) {
    __builtin_amdgcn_global_load_lds(
        (const __attribute__((address_space(1))) void*)g,
        (__attribute__((address_space(3))) void*)l, 16, 0, 0);
}

// counted-vmcnt barrier pair (T4)
#define WAIT_BAR(N) do {                                              \
    asm volatile("s_waitcnt vmcnt(" #N ")" ::: "memory");             \
    __builtin_amdgcn_sched_barrier(0);                                \
    __builtin_amdgcn_s_barrier();                                     \
    __builtin_amdgcn_sched_barrier(0);                                \
} while (0)
#define BAR_ONLY() do {                                               \
    __builtin_amdgcn_sched_barrier(0);                                \
    __builtin_amdgcn_s_barrier();                                     \
    __builtin_amdgcn_sched_barrier(0);                                \
} while (0)

// ---------------------------------------------------------------- prep (8-wide vectorized h conversion)
__global__ __launch_bounds__(256) void prep_kernel(
    const float* __restrict__ h, const float* __restrict__ Wpre,
    const float* __restrict__ Wpost, const float* __restrict__ Wmix,
    short* __restrict__ hbf, short* __restrict__ wpreT2,
    short* __restrict__ wpostT, short* __restrict__ wmixT,
    int* __restrict__ degc, int* __restrict__ cursor, int* __restrict__ gcnt)
{
    long i = (long)blockIdx.x * 256 + threadIdx.x;
    if (i < 800000) {   // 6.4M elements, 8 per thread
        float4 a = *(const float4*)(h + i * 8);
        float4 b = *(const float4*)(h + i * 8 + 4);
        int4 v;
        v.x = (int)pk2(a.x, a.y); v.y = (int)pk2(a.z, a.w);
        v.z = (int)pk2(b.x, b.y); v.w = (int)pk2(b.z, b.w);
        *(int4*)(hbf + i * 8) = v;
        return;
    }
    i -= 800000;
    if (i < 32768) {  // wpreT2[n][k]: n<128 -> Wpre[k][n] (top); n>=128 -> Wpre[k+128][n-128]
        int n = i >> 7, k = i & 127;
        float v = (n < 128) ? Wpre[k * 128 + n] : Wpre[(k + 128) * 128 + (n - 128)];
        wpreT2[n * 128 + k] = f2b(v);
        return;
    }
    i -= 32768;
    if (i < 212992) { int k = i >> 7, n = i & 127; wpostT[n * 1664 + k] = f2b(Wpost[k * 128 + n]); return; }
    i -= 212992;
    if (i < 16384) { int k = i >> 7, n = i & 127; wmixT[n * 128 + k] = f2b(Wmix[k * 128 + n]); return; }
    i -= 16384;
    if (i < N_NODES) { degc[i] = 0; return; }
    i -= N_NODES;
    if (i < N_NODES) { cursor[i] = 0; return; }
    i -= N_NODES;
    if (i == 0) *gcnt = 0;
}
#define PREP_BLOCKS ((800000 + 32768 + 212992 + 16384 + 2 * N_NODES + 1 + 255) / 256)

// ---------------------------------------------------------------- degree histogram
__global__ __launch_bounds__(256) void hist_kernel(const int* __restrict__ edst, int* __restrict__ degc) {
    int e = blockIdx.x * 256 + threadIdx.x;
    if (e < N_EDGES) atomicAdd(&degc[edst[e]], 1);
}

// ---------------------------------------------------------------- range alloc (replaces 3-kernel scan)
// off[n] = start of node n's contiguous range; ranges disjoint, order arbitrary.
// wave-aggregated: shfl inclusive scan + one atomicAdd per wave.
__global__ __launch_bounds__(256) void alloc_kernel(const int* __restrict__ degc,
                                                    int* __restrict__ off, int* __restrict__ gcnt) {
    int n = blockIdx.x * 256 + threadIdx.x;
    int d = (n < N_NODES) ? degc[n] : 0;
    int pre = d;
#pragma unroll
    for (int o = 1; o < 64; o <<= 1) {
        int t = __shfl_up(pre, o);
        if ((threadIdx.x & 63) >= o) pre += t;
    }
    int base = 0;
    if ((threadIdx.x & 63) == 63) base = atomicAdd(gcnt, pre);   // pre = wave total at lane 63
    base = __shfl(base, 63);
    if (n < N_NODES) off[n] = base + pre - d;                    // exclusive within wave
}

// ---------------------------------------------------------------- scatter srcs into dst-sorted order
__global__ __launch_bounds__(256) void scatter_kernel(const int* __restrict__ esrc, const int* __restrict__ edst,
                                                      const int* __restrict__ off, int* __restrict__ cursor,
                                                      int* __restrict__ srcs) {
    int e = blockIdx.x * 256 + threadIdx.x;
    if (e < N_EDGES) {
        int d = edst[e];
        int p = off[d] + atomicAdd(&cursor[d], 1);
        srcs[p] = esrc[e];
    }
}

// ---------------------------------------------------------------- shared GEMM stage/compute helpers
// stage one 128x64 A tile (node rows): 4 gld_lds per wave (256-thread block)
__device__ __forceinline__ void stageA_t(short* ldsT, const short* src, int rs, int co,
                                         int bn, int wv, int lane) {
    const int sub = lane >> 3, seg = lane & 7;
    const int sg = (seg ^ sub) * 8;          // pre-swizzled global seg (row&7 == sub)
#pragma unroll
    for (int t = 0; t < 4; t++) {
        int i = wv * 4 + t;
        int row = i * 8 + sub;
        int n = bn + row; if (n >= N_NODES) n = N_NODES - 1;
        gld_lds16(src + (long)n * rs + co + sg, ldsT + i * 512);
    }
}
// stage one 128x64 B tile (weight rows, no clamp)
__device__ __forceinline__ void stageB_t(short* ldsT, const short* src, int rs, int co,
                                         int wv, int lane) {
    const int sub = lane >> 3, seg = lane & 7;
    const int sg = (seg ^ sub) * 8;
#pragma unroll
    for (int t = 0; t < 4; t++) {
        int i = wv * 4 + t;
        int row = i * 8 + sub;
        gld_lds16(src + (long)row * rs + co + sg, ldsT + i * 512);
    }
}

#define MFMA_ITER(AB, BB, ACC)                                                      \
    {                                                                               \
        _Pragma("unroll")                                                           \
        for (int ks = 0; ks < 2; ks++) {                                            \
            const int qx = (((ks * 4 + quad) ^ r7) * 8);                            \
            bf16x8 a0 = *(const bf16x8*)&(AB)[(wv * 32 + lm) * 64 + qx];            \
            bf16x8 a1 = *(const bf16x8*)&(AB)[(wv * 32 + 16 + lm) * 64 + qx];       \
            _Pragma("unroll")                                                       \
            for (int ct = 0; ct < 8; ct++) {                                        \
                bf16x8 b = *(const bf16x8*)&(BB)[(ct * 16 + lm) * 64 + qx];         \
                ACC[0][ct] = __builtin_amdgcn_mfma_f32_16x16x32_bf16(b, a0, ACC[0][ct], 0, 0, 0); \
                ACC[1][ct] = __builtin_amdgcn_mfma_f32_16x16x32_bf16(b, a1, ACC[1][ct], 0, 0, 0); \
            }                                                                       \
        }                                                                           \
    }

// ---------------------------------------------------------------- PQ = h @ [Wtop | Wbot] (+bias on Q)
// K = 128 (2 chunks of 64). Counted-vmcnt: k1 loads hide under k0 MFMA; 2 barriers total.
__global__ __launch_bounds__(256, 2) void gemm_pq_kernel(
    const short* __restrict__ hbf, const short* __restrict__ wpreT2,
    const float* __restrict__ bpre, short* __restrict__ PQ)
{
    __shared__ __align__(16) short As[2][8192];
    __shared__ __align__(16) short Bs[2][8192];

    const int tid = threadIdx.x;
    const int cg = blockIdx.x & 1;            // 0 = P cols, 1 = Q cols
    const int bn = (blockIdx.x >> 1) * 128;
    const int lane = tid & 63, wv = tid >> 6;
    const int lm = lane & 15, quad = lane >> 4;
    const int r7 = lm & 7;
    const short* Bsrc = wpreT2 + cg * 128 * 128;   // this block's 128 weight rows, [n][k=128]

    f32x4 acc[2][8];
#pragma unroll
    for (int a = 0; a < 2; a++)
#pragma unroll
        for (int b = 0; b < 8; b++) acc[a][b] = (f32x4){0.f, 0.f, 0.f, 0.f};

    // issue k0 (8) then k1 (8) -> 16 in flight
    stageA_t(As[0], hbf, 128, 0, bn, wv, lane);
    stageB_t(Bs[0], Bsrc, 128, 0, wv, lane);
    stageA_t(As[1], hbf, 128, 64, bn, wv, lane);
    stageB_t(Bs[1], Bsrc, 128, 64, wv, lane);
    WAIT_BAR(8);                       // k0 landed (all waves)
    MFMA_ITER(As[0], Bs[0], acc);
    WAIT_BAR(0);                       // k1 landed
    MFMA_ITER(As[1], Bs[1], acc);

#pragma unroll
    for (int rt = 0; rt < 2; rt++) {
        int row = wv * 32 + rt * 16 + lm;
        int n = bn + row;
        if (n >= N_NODES) continue;
        short* dst = PQ + (long)n * 256;
#pragma unroll
        for (int ct = 0; ct < 8; ct++) {
            int col = cg * 128 + ct * 16 + quad * 4;
            float v0 = acc[rt][ct][0], v1 = acc[rt][ct][1], v2 = acc[rt][ct][2], v3 = acc[rt][ct][3];
            if (cg) {
                float4 bv = *(const float4*)(bpre + (col - 128));
                v0 += bv.x; v1 += bv.y; v2 += bv.z; v3 += bv.w;
            }
            int2 pkd; pkd.x = (int)pk2(v0, v1); pkd.y = (int)pk2(v2, v3);
            *(int2*)(dst + col) = pkd;
        }
    }
}

// ---------------------------------------------------------------- fused edge compute + stats: one wave per node
__global__ __launch_bounds__(256) void edgestats_kernel(
    const short* __restrict__ PQ, const int* __restrict__ srcs,
    const int* __restrict__ off, const int* __restrict__ degc, short* __restrict__ aggbf)
{
    const int wv = threadIdx.x >> 6, lane = threadIdx.x & 63;
    const int n = blockIdx.x * 4 + wv;            // grid 12500 * 4 waves = 50000
    const unsigned* Pb = (const unsigned*)PQ;     // u32 view: row = 128 u32 (P=0..63, Q=64..127)

    const int s0 = __builtin_amdgcn_readfirstlane(off[n]);
    const int s1 = s0 + __builtin_amdgcn_readfirstlane(degc[n]);

    unsigned qu = Pb[(long)n * 128 + 64 + lane];
    const float qa = blo(qu), qb = bhi(qu);

    float sA = 0.f, sB = 0.f, qA = 0.f, qB = 0.f;
    float mxA = -1e30f, mxB = -1e30f, mnA = 1e30f, mnB = 1e30f;

    int p = s0;
    for (; p + 8 <= s1; p += 8) {
        int idx[8];
#pragma unroll
        for (int j = 0; j < 8; j++) idx[j] = srcs[p + j];
        unsigned u[8];
#pragma unroll
        for (int j = 0; j < 8; j++) u[j] = Pb[(long)idx[j] * 128 + lane];
#pragma unroll
        for (int j = 0; j < 8; j++) {
            float a = blo(u[j]) + qa; a = a > 0.f ? a : 0.f;
            float b = bhi(u[j]) + qb; b = b > 0.f ? b : 0.f;
            sA += a; sB += b; qA += a * a; qB += b * b;
            mxA = fmaxf(mxA, a); mxB = fmaxf(mxB, b);
            mnA = fminf(mnA, a); mnB = fminf(mnB, b);
        }
    }
    if (p + 4 <= s1) {
        int idx[4];
#pragma unroll
        for (int j = 0; j < 4; j++) idx[j] = srcs[p + j];
        unsigned u[4];
#pragma unroll
        for (int j = 0; j < 4; j++) u[j] = Pb[(long)idx[j] * 128 + lane];
#pragma unroll
        for (int j = 0; j < 4; j++) {
            float a = blo(u[j]) + qa; a = a > 0.f ? a : 0.f;
            float b = bhi(u[j]) + qb; b = b > 0.f ? b : 0.f;
            sA += a; sB += b; qA += a * a; qB += b * b;
            mxA = fmaxf(mxA, a); mxB = fmaxf(mxB, b);
            mnA = fminf(mnA, a); mnB = fminf(mnB, b);
        }
        p += 4;
    }
    for (; p < s1; p++) {
        unsigned u = Pb[(long)srcs[p] * 128 + lane];
        float a = blo(u) + qa; a = a > 0.f ? a : 0.f;
        float b = bhi(u) + qb; b = b > 0.f ? b : 0.f;
        sA += a; sB += b; qA += a * a; qB += b * b;
        mxA = fmaxf(mxA, a); mxB = fmaxf(mxB, b);
        mnA = fminf(mnA, a); mnB = fminf(mnB, b);
    }

    float inv = 1.0f / (float)(s1 - s0);   // deg >= 1 guaranteed (self-loops)
    float mA = sA * inv, mB = sB * inv;
    float vA = qA * inv - mA * mA; vA = vA > 0.f ? vA : 0.f;
    float vB = qB * inv - mB * mB; vB = vB > 0.f ? vB : 0.f;
    float stA = sqrtf(vA + EPS_V), stB = sqrtf(vB + EPS_V);

    unsigned* ag = (unsigned*)(aggbf + (long)n * 512);
    ag[lane]       = pk2(mA, mB);
    ag[64 + lane]  = pk2(mxA, mxB);
    ag[128 + lane] = pk2(mnA, mnB);
    ag[192 + lane] = pk2(stA, stB);
}

// ---------------------------------------------------------------- fused post + mix per node
// v4 structure (best measured: 53.4 us): 128-node tile, folded degree-scalers
// (3 accumulators), gld_lds staging into XOR-swizzled tiles, counted-vmcnt pipeline.
__global__ __launch_bounds__(256, 2) void node_kernel(
    const float* __restrict__ h, const short* __restrict__ hbf, const short* __restrict__ aggbf,
    const int* __restrict__ degc, const short* __restrict__ wpostT, const float* __restrict__ bpost,
    const short* __restrict__ wmixT, const float* __restrict__ bmix, float* __restrict__ out)
{
    __shared__ __align__(16) short As[2][8192];   // 2 x (128 rows x 64 shorts)
    __shared__ __align__(16) short Bs[2][8192];
    __shared__ float sAmp[128], sAtt[128];

    const int tid = threadIdx.x;
    const int bn = blockIdx.x * 128;
    const int lane = tid & 63, wv = tid >> 6;
    const int lm = lane & 15, quad = lane >> 4;
    const int r7 = lm & 7;

    if (tid < 128) {
        int n = bn + tid; if (n >= N_NODES) n = N_NODES - 1;
        float d = (float)degc[n];
        float ld = logf(d + 1.0f);
        sAmp[tid] = ld * (1.0f / AVG_D_LOG);
        sAtt[tid] = AVG_D_LOG / ld;
    }
    __syncthreads();   // drains degc load -> vmcnt baseline 0 for exact counted waits

    f32x4 accI[2][8], accM[2][8], accT[2][8];
#pragma unroll
    for (int a = 0; a < 2; a++)
#pragma unroll
        for (int b = 0; b < 8; b++) {
            accI[a][b] = (f32x4){0.f, 0.f, 0.f, 0.f};
            accM[a][b] = (f32x4){0.f, 0.f, 0.f, 0.f};
            accT[a][b] = (f32x4){0.f, 0.f, 0.f, 0.f};
        }

    // K-chunk map (64-wide): B chunks 0-1 = h, 2-9 = id, 10-17 = amp, 18-25 = att.
    // A tiles: h0,h1, agg j (j=0..7, co = (j>>1)*128 + (j&1)*64) shared by B {2+j,10+j,18+j}.

    // prologue: Ah0, Bc0 -> in flight 8
    stageA_t(As[0], hbf, 128, 0, bn, wv, lane);
    stageB_t(Bs[0], wpostT, 1664, 0, wv, lane);

    // p0: issue Ah1+Bc1 (8); wait prologue 8; compute h0 x c0
    stageA_t(As[1], hbf, 128, 64, bn, wv, lane);
    stageB_t(Bs[1], wpostT, 1664, 64, wv, lane);
    WAIT_BAR(8);
    MFMA_ITER(As[0], Bs[0], accI);
    BAR_ONLY();

    // p1: issue Bid0+Aagg0 (8); wait p0's 8; compute h1 x c1
    stageB_t(Bs[0], wpostT, 1664, 2 * 64, wv, lane);
    stageA_t(As[0], aggbf, 512, 0, bn, wv, lane);
    WAIT_BAR(8);
    MFMA_ITER(As[1], Bs[1], accI);
    BAR_ONLY();

    int pb = 0;   // Bs parity holding the id chunk of current j; A tile = As[j&1]
    for (int j = 0; j < 8; j++) {
        const short* Ac = As[j & 1];
        // s0 (id_j, reads Bs[pb]): issue Bamp_j (+ Aagg_{j+1} if j<7)
        stageB_t(Bs[pb ^ 1], wpostT, 1664, (10 + j) * 64, wv, lane);
        if (j < 7) {
            int jn = j + 1;
            stageA_t(As[jn & 1], aggbf, 512, (jn >> 1) * 128 + (jn & 1) * 64, bn, wv, lane);
            WAIT_BAR(8);
        } else {
            WAIT_BAR(4);
        }
        MFMA_ITER(Ac, Bs[pb], accI);
        BAR_ONLY();

        // s1 (amp_j, reads Bs[pb^1]): issue Batt_j
        stageB_t(Bs[pb], wpostT, 1664, (18 + j) * 64, wv, lane);
        if (j < 7) { WAIT_BAR(8); } else { WAIT_BAR(4); }
        MFMA_ITER(Ac, Bs[pb ^ 1], accM);
        BAR_ONLY();

        // s2 (att_j, reads Bs[pb]): issue Bid_{j+1} (or mixB0 at j=7)
        if (j < 7) stageB_t(Bs[pb ^ 1], wpostT, 1664, (3 + j) * 64, wv, lane);
        else       stageB_t(Bs[pb ^ 1], wmixT, 128, 0, wv, lane);   // mixB0 -> Bs[0]
        WAIT_BAR(4);
        MFMA_ITER(Ac, Bs[pb], accT);
        BAR_ONLY();
        pb ^= 1;
    }
    // after loop pb == 0; mixB0 in flight -> Bs[0]

    // combine: issue mixB1 -> Bs[1]; hp = relu(accI + amp*accM + att*accT + bpost)
    stageB_t(Bs[1], wmixT, 128, 64, wv, lane);

    const float am0 = sAmp[wv * 32 + lm],      at0 = sAtt[wv * 32 + lm];
    const float am1 = sAmp[wv * 32 + 16 + lm], at1 = sAtt[wv * 32 + 16 + lm];
#pragma unroll
    for (int rt = 0; rt < 2; rt++) {
        const float am = rt ? am1 : am0, at = rt ? at1 : at0;
        const int row = wv * 32 + rt * 16 + lm;
#pragma unroll
        for (int ct = 0; ct < 8; ct++) {
            float4 bv = *(const float4*)(bpost + ct * 16 + quad * 4);
            float v0 = accI[rt][ct][0] + am * accM[rt][ct][0] + at * accT[rt][ct][0] + bv.x;
            float v1 = accI[rt][ct][1] + am * accM[rt][ct][1] + at * accT[rt][ct][1] + bv.y;
            float v2 = accI[rt][ct][2] + am * accM[rt][ct][2] + at * accT[rt][ct][2] + bv.z;
            float v3 = accI[rt][ct][3] + am * accM[rt][ct][3] + at * accT[rt][ct][3] + bv.w;
            v0 = v0 > 0.f ? v0 : 0.f; v1 = v1 > 0.f ? v1 : 0.f;
            v2 = v2 > 0.f ? v2 : 0.f; v3 = v3 > 0.f ? v3 : 0.f;
            int2 pkd; pkd.x = (int)pk2(v0, v1); pkd.y = (int)pk2(v2, v3);
            const int cb = (ct & 3) * 32 + quad * 8;           // byte off within 128B row
            const int sb = ((((cb >> 4) ^ r7) << 4) | (cb & 15));
            *(int2*)((char*)As[ct >> 2] + row * 128 + sb) = pkd;
        }
    }
    __syncthreads();   // drains mixB loads (vmcnt) + hp writes (lgkm); single full drain

    // ---- mix GEMM: K=128, both chunks resident
    f32x4 accO[2][8];
#pragma unroll
    for (int a = 0; a < 2; a++)
#pragma unroll
        for (int b = 0; b < 8; b++) accO[a][b] = (f32x4){0.f, 0.f, 0.f, 0.f};
#pragma unroll
    for (int kc = 0; kc < 2; kc++) {
        MFMA_ITER(As[kc], Bs[kc], accO);
    }

    // epilogue: out = h + leaky_relu(accO + b_mix)
#pragma unroll
    for (int rt = 0; rt < 2; rt++) {
        int row = wv * 32 + rt * 16 + lm;
        int n = bn + row;
        if (n >= N_NODES) continue;
#pragma unroll
        for (int ct = 0; ct < 8; ct++) {
            int col = ct * 16 + quad * 4;
            float4 bv = *(const float4*)(bmix + col);
            float4 hv = *(const float4*)(h + (long)n * 128 + col);
            float4 o;
            float v0 = accO[rt][ct][0] + bv.x; v0 = v0 > 0.f ? v0 : 0.01f * v0; o.x = hv.x + v0;
            float v1 = accO[rt][ct][1] + bv.y; v1 = v1 > 0.f ? v1 : 0.01f * v1; o.y = hv.y + v1;
            float v2 = accO[rt][ct][2] + bv.z; v2 = v2 > 0.f ? v2 : 0.01f * v2; o.z = hv.z + v2;
            float v3 = accO[rt][ct][3] + bv.w; v3 = v3 > 0.f ? v3 : 0.01f * v3; o.w = hv.w + v3;
            *(float4*)(out + (long)n * 128 + col) = o;
        }
    }
}

extern "C" void kernel_launch(void* const* d_in, const int* in_sizes, int n_in,
                              void* d_out, int out_size, void* d_ws, size_t ws_size,
                              hipStream_t stream) {
    const float* h     = (const float*)d_in[0];
    const int*   esrc  = (const int*)d_in[1];
    const int*   edst  = (const int*)d_in[2];
    const float* Wpre  = (const float*)d_in[3];
    const float* bpre  = (const float*)d_in[4];
    const float* Wpost = (const float*)d_in[5];
    const float* bpost = (const float*)d_in[6];
    const float* Wmix  = (const float*)d_in[7];
    const float* bmix  = (const float*)d_in[8];
    float* out = (float*)d_out;
    char* ws = (char*)d_ws;

    short* PQ     = (short*)(ws + PQ_B);
    short* aggbf  = (short*)(ws + AGG_B);
    short* hbf    = (short*)(ws + HBF_B);
    short* wpreT2 = (short*)(ws + WPRET2_B);
    short* wpostT = (short*)(ws + WPOSTT_B);
    short* wmixT  = (short*)(ws + WMIXT_B);
    int*   degc   = (int*)(ws + DEGC_B);
    int*   off    = (int*)(ws + OFF_B);
    int*   cursor = (int*)(ws + CUR_B);
    int*   srcs   = (int*)(ws + SRCS_B);
    int*   gcnt   = (int*)(ws + GCNT_B);

    prep_kernel<<<PREP_BLOCKS, 256, 0, stream>>>(h, Wpre, Wpost, Wmix, hbf, wpreT2, wpostT, wmixT, degc, cursor, gcnt);
    hist_kernel<<<(N_EDGES + 255) / 256, 256, 0, stream>>>(edst, degc);
    alloc_kernel<<<(N_NODES + 255) / 256, 256, 0, stream>>>(degc, off, gcnt);
    scatter_kernel<<<(N_EDGES + 255) / 256, 256, 0, stream>>>(esrc, edst, off, cursor, srcs);
    gemm_pq_kernel<<<((N_NODES + 127) / 128) * 2, 256, 0, stream>>>(hbf, wpreT2, bpre, PQ);
    edgestats_kernel<<<N_NODES / 4, 256, 0, stream>>>(PQ, srcs, off, degc, aggbf);
    node_kernel<<<(N_NODES + 127) / 128, 256, 0, stream>>>(h, hbf, aggbf, degc, wpostT, bpost, wmixT, bmix, out);
}

// Round 8
// 244.393 us; speedup vs baseline: 1.1186x; 1.0415x over previous
//
#include <hip/hip_runtime.h>
#include <hip/hip_bf16.h>

#define N_NODES 50000
#define N_EDGES 600000
#define D 128

constexpr float AVG_D_LOG = 1.6094379124341003f;  // log(5)
constexpr float EPS_V = 1e-5f;

// ---- workspace byte offsets (total ~93.1 MB)
#define PQ_B     0ul           // bf16 [50000][256]  P|Q rows     = 25,600,000
#define AGG_B    25600000ul    // bf16 [50000][512]  mean|max|min|std = 51,200,000
#define HBF_B    76800000ul    // bf16 [50000][128]
#define WPRET2_B 89600000ul    // bf16 [256][128]   (P cols | Q cols, [n][k])
#define WPOSTT_B 89665536ul    // bf16 [128][1664]
#define WMIXT_B  90091520ul    // bf16 [128][128]
#define DEGC_B   90124288ul    // int  [50000]
#define OFF_B    90324288ul    // int  [50016]
#define CUR_B    90524352ul    // int  [50000]
#define SRCS_B   90724352ul    // int  [600000]  src ids in dst-sorted order
#define GCNT_B   93124352ul    // int  [1]  global range allocator

typedef __attribute__((ext_vector_type(8))) short bf16x8;
typedef __attribute__((ext_vector_type(4))) float f32x4;

__device__ __forceinline__ short f2b(float f) {
    unsigned u = __builtin_bit_cast(unsigned, f);
    u += 0x7fffu + ((u >> 16) & 1u);   // RNE
    return (short)(u >> 16);
}
__device__ __forceinline__ unsigned pk2(float a, float b) {
    return (unsigned)(unsigned short)f2b(a) | ((unsigned)(unsigned short)f2b(b) << 16);
}
__device__ __forceinline__ float blo(unsigned u) { return __uint_as_float(u << 16); }
__device__ __forceinline__ float bhi(unsigned u) { return __uint_as_float(u & 0xffff0000u); }

// async global->LDS, 16B per lane; LDS dest = wave-uniform base + lane*16
__device__ __forceinline__ void gld_lds16(const void* g, void* l) {
    __builtin_amdgcn_global_load_lds(
        (const __attribute__((address_space(1))) void*)g,
        (__attribute__((address_space(3))) void*)l, 16, 0, 0);
}

// counted-vmcnt barrier pair (T4)
#define WAIT_BAR(N) do {                                              \
    asm volatile("s_waitcnt vmcnt(" #N ")" ::: "memory");             \
    __builtin_amdgcn_sched_barrier(0);                                \
    __builtin_amdgcn_s_barrier();                                     \
    __builtin_amdgcn_sched_barrier(0);                                \
} while (0)
#define BAR_ONLY() do {                                               \
    __builtin_amdgcn_sched_barrier(0);                                \
    __builtin_amdgcn_s_barrier();                                     \
    __builtin_amdgcn_sched_barrier(0);                                \
} while (0)
#define SB0() __builtin_amdgcn_sched_barrier(0)

// ---------------------------------------------------------------- prep (8-wide vectorized h conversion)
__global__ __launch_bounds__(256) void prep_kernel(
    const float* __restrict__ h, const float* __restrict__ Wpre,
    const float* __restrict__ Wpost, const float* __restrict__ Wmix,
    short* __restrict__ hbf, short* __restrict__ wpreT2,
    short* __restrict__ wpostT, short* __restrict__ wmixT,
    int* __restrict__ degc, int* __restrict__ cursor, int* __restrict__ gcnt)
{
    long i = (long)blockIdx.x * 256 + threadIdx.x;
    if (i < 800000) {   // 6.4M elements, 8 per thread
        float4 a = *(const float4*)(h + i * 8);
        float4 b = *(const float4*)(h + i * 8 + 4);
        int4 v;
        v.x = (int)pk2(a.x, a.y); v.y = (int)pk2(a.z, a.w);
        v.z = (int)pk2(b.x, b.y); v.w = (int)pk2(b.z, b.w);
        *(int4*)(hbf + i * 8) = v;
        return;
    }
    i -= 800000;
    if (i < 32768) {  // wpreT2[n][k]: n<128 -> Wpre[k][n] (top); n>=128 -> Wpre[k+128][n-128]
        int n = i >> 7, k = i & 127;
        float v = (n < 128) ? Wpre[k * 128 + n] : Wpre[(k + 128) * 128 + (n - 128)];
        wpreT2[n * 128 + k] = f2b(v);
        return;
    }
    i -= 32768;
    if (i < 212992) { int k = i >> 7, n = i & 127; wpostT[n * 1664 + k] = f2b(Wpost[k * 128 + n]); return; }
    i -= 212992;
    if (i < 16384) { int k = i >> 7, n = i & 127; wmixT[n * 128 + k] = f2b(Wmix[k * 128 + n]); return; }
    i -= 16384;
    if (i < N_NODES) { degc[i] = 0; return; }
    i -= N_NODES;
    if (i < N_NODES) { cursor[i] = 0; return; }
    i -= N_NODES;
    if (i == 0) *gcnt = 0;
}
#define PREP_BLOCKS ((800000 + 32768 + 212992 + 16384 + 2 * N_NODES + 1 + 255) / 256)

// ---------------------------------------------------------------- degree histogram
__global__ __launch_bounds__(256) void hist_kernel(const int* __restrict__ edst, int* __restrict__ degc) {
    int e = blockIdx.x * 256 + threadIdx.x;
    if (e < N_EDGES) atomicAdd(&degc[edst[e]], 1);
}

// ---------------------------------------------------------------- range alloc (replaces 3-kernel scan)
__global__ __launch_bounds__(256) void alloc_kernel(const int* __restrict__ degc,
                                                    int* __restrict__ off, int* __restrict__ gcnt) {
    int n = blockIdx.x * 256 + threadIdx.x;
    int d = (n < N_NODES) ? degc[n] : 0;
    int pre = d;
#pragma unroll
    for (int o = 1; o < 64; o <<= 1) {
        int t = __shfl_up(pre, o);
        if ((threadIdx.x & 63) >= o) pre += t;
    }
    int base = 0;
    if ((threadIdx.x & 63) == 63) base = atomicAdd(gcnt, pre);   // pre = wave total at lane 63
    base = __shfl(base, 63);
    if (n < N_NODES) off[n] = base + pre - d;                    // exclusive within wave
}

// ---------------------------------------------------------------- scatter srcs into dst-sorted order
__global__ __launch_bounds__(256) void scatter_kernel(const int* __restrict__ esrc, const int* __restrict__ edst,
                                                      const int* __restrict__ off, int* __restrict__ cursor,
                                                      int* __restrict__ srcs) {
    int e = blockIdx.x * 256 + threadIdx.x;
    if (e < N_EDGES) {
        int d = edst[e];
        int p = off[d] + atomicAdd(&cursor[d], 1);
        srcs[p] = esrc[e];
    }
}

// ---------------------------------------------------------------- shared GEMM stage/compute helpers
// stage one 128x64 A tile (node rows): 4 gld_lds per wave (256-thread block)
__device__ __forceinline__ void stageA_t(short* ldsT, const short* src, int rs, int co,
                                         int bn, int wv, int lane) {
    const int sub = lane >> 3, seg = lane & 7;
    const int sg = (seg ^ sub) * 8;          // pre-swizzled global seg (row&7 == sub)
#pragma unroll
    for (int t = 0; t < 4; t++) {
        int i = wv * 4 + t;
        int row = i * 8 + sub;
        int n = bn + row; if (n >= N_NODES) n = N_NODES - 1;
        gld_lds16(src + (long)n * rs + co + sg, ldsT + i * 512);
    }
}
// stage one 128x64 B tile (weight rows, no clamp)
__device__ __forceinline__ void stageB_t(short* ldsT, const short* src, int rs, int co,
                                         int wv, int lane) {
    const int sub = lane >> 3, seg = lane & 7;
    const int sg = (seg ^ sub) * 8;
#pragma unroll
    for (int t = 0; t < 4; t++) {
        int i = wv * 4 + t;
        int row = i * 8 + sub;
        gld_lds16(src + (long)row * rs + co + sg, ldsT + i * 512);
    }
}
// load 4 A-fragments (rt x ks) for this wave's 32 rows, K=64 chunk at co, direct global->reg
__device__ __forceinline__ void loadAfr(bf16x8* a, const short* src, int rs, int co,
                                        int bn, int wv, int lm, int quad) {
#pragma unroll
    for (int rt = 0; rt < 2; rt++)
#pragma unroll
        for (int ks = 0; ks < 2; ks++) {
            int n = bn + wv * 32 + rt * 16 + lm; if (n >= N_NODES) n = N_NODES - 1;
            a[rt * 2 + ks] = *(const bf16x8*)(src + (long)n * rs + co + ks * 32 + quad * 8);
        }
}

// MFMA group, A from LDS (used by gemm_pq and node mix phase)
#define MFMA_ITER(AB, BB, ACC)                                                      \
    {                                                                               \
        _Pragma("unroll")                                                           \
        for (int ks = 0; ks < 2; ks++) {                                            \
            const int qx = (((ks * 4 + quad) ^ r7) * 8);                            \
            bf16x8 a0 = *(const bf16x8*)&(AB)[(wv * 32 + lm) * 64 + qx];            \
            bf16x8 a1 = *(const bf16x8*)&(AB)[(wv * 32 + 16 + lm) * 64 + qx];       \
            _Pragma("unroll")                                                       \
            for (int ct = 0; ct < 8; ct++) {                                        \
                bf16x8 b = *(const bf16x8*)&(BB)[(ct * 16 + lm) * 64 + qx];         \
                ACC[0][ct] = __builtin_amdgcn_mfma_f32_16x16x32_bf16(b, a0, ACC[0][ct], 0, 0, 0); \
                ACC[1][ct] = __builtin_amdgcn_mfma_f32_16x16x32_bf16(b, a1, ACC[1][ct], 0, 0, 0); \
            }                                                                       \
        }                                                                           \
    }

// MFMA group, A from registers (AF = bf16x8[4]: rt0ks0,rt0ks1,rt1ks0,rt1ks1)
#define MFMA_RG(BB, AF, ACC, FRESH)                                                 \
    {                                                                               \
        __builtin_amdgcn_s_setprio(1);                                              \
        _Pragma("unroll")                                                           \
        for (int ks = 0; ks < 2; ks++) {                                            \
            const int qx = ((ks * 4 + quad) ^ r7) * 8;                              \
            _Pragma("unroll")                                                       \
            for (int ct = 0; ct < 8; ct++) {                                        \
                bf16x8 b = *(const bf16x8*)&(BB)[(ct * 16 + lm) * 64 + qx];         \
                f32x4 c0 = ((FRESH) && ks == 0) ? (f32x4){0.f, 0.f, 0.f, 0.f} : ACC[0][ct]; \
                f32x4 c1 = ((FRESH) && ks == 0) ? (f32x4){0.f, 0.f, 0.f, 0.f} : ACC[1][ct]; \
                ACC[0][ct] = __builtin_amdgcn_mfma_f32_16x16x32_bf16(b, (AF)[ks], c0, 0, 0, 0); \
                ACC[1][ct] = __builtin_amdgcn_mfma_f32_16x16x32_bf16(b, (AF)[2 + ks], c1, 0, 0, 0); \
            }                                                                       \
        }                                                                           \
        __builtin_amdgcn_s_setprio(0);                                              \
    }

// ---------------------------------------------------------------- PQ = h @ [Wtop | Wbot] (+bias on Q)
// K = 128 (2 chunks of 64). Counted-vmcnt: k1 loads hide under k0 MFMA; 2 barriers total.
__global__ __launch_bounds__(256, 2) void gemm_pq_kernel(
    const short* __restrict__ hbf, const short* __restrict__ wpreT2,
    const float* __restrict__ bpre, short* __restrict__ PQ)
{
    __shared__ __align__(16) short As[2][8192];
    __shared__ __align__(16) short Bs[2][8192];

    const int tid = threadIdx.x;
    const int cg = blockIdx.x & 1;            // 0 = P cols, 1 = Q cols
    const int bn = (blockIdx.x >> 1) * 128;
    const int lane = tid & 63, wv = tid >> 6;
    const int lm = lane & 15, quad = lane >> 4;
    const int r7 = lm & 7;
    const short* Bsrc = wpreT2 + cg * 128 * 128;   // this block's 128 weight rows, [n][k=128]

    f32x4 acc[2][8];
#pragma unroll
    for (int a = 0; a < 2; a++)
#pragma unroll
        for (int b = 0; b < 8; b++) acc[a][b] = (f32x4){0.f, 0.f, 0.f, 0.f};

    // issue k0 (8) then k1 (8) -> 16 in flight
    stageA_t(As[0], hbf, 128, 0, bn, wv, lane);
    stageB_t(Bs[0], Bsrc, 128, 0, wv, lane);
    stageA_t(As[1], hbf, 128, 64, bn, wv, lane);
    stageB_t(Bs[1], Bsrc, 128, 64, wv, lane);
    WAIT_BAR(8);                       // k0 landed (all waves)
    MFMA_ITER(As[0], Bs[0], acc);
    WAIT_BAR(0);                       // k1 landed
    MFMA_ITER(As[1], Bs[1], acc);

#pragma unroll
    for (int rt = 0; rt < 2; rt++) {
        int row = wv * 32 + rt * 16 + lm;
        int n = bn + row;
        if (n >= N_NODES) continue;
        short* dst = PQ + (long)n * 256;
#pragma unroll
        for (int ct = 0; ct < 8; ct++) {
            int col = cg * 128 + ct * 16 + quad * 4;
            float v0 = acc[rt][ct][0], v1 = acc[rt][ct][1], v2 = acc[rt][ct][2], v3 = acc[rt][ct][3];
            if (cg) {
                float4 bv = *(const float4*)(bpre + (col - 128));
                v0 += bv.x; v1 += bv.y; v2 += bv.z; v3 += bv.w;
            }
            int2 pkd; pkd.x = (int)pk2(v0, v1); pkd.y = (int)pk2(v2, v3);
            *(int2*)(dst + col) = pkd;
        }
    }
}

// ---------------------------------------------------------------- fused edge compute + stats: one wave per node
__global__ __launch_bounds__(256) void edgestats_kernel(
    const short* __restrict__ PQ, const int* __restrict__ srcs,
    const int* __restrict__ off, const int* __restrict__ degc, short* __restrict__ aggbf)
{
    const int wv = threadIdx.x >> 6, lane = threadIdx.x & 63;
    const int n = blockIdx.x * 4 + wv;            // grid 12500 * 4 waves = 50000
    const unsigned* Pb = (const unsigned*)PQ;     // u32 view: row = 128 u32 (P=0..63, Q=64..127)

    const int s0 = __builtin_amdgcn_readfirstlane(off[n]);
    const int s1 = s0 + __builtin_amdgcn_readfirstlane(degc[n]);

    unsigned qu = Pb[(long)n * 128 + 64 + lane];
    const float qa = blo(qu), qb = bhi(qu);

    float sA = 0.f, sB = 0.f, qA = 0.f, qB = 0.f;
    float mxA = -1e30f, mxB = -1e30f, mnA = 1e30f, mnB = 1e30f;

    int p = s0;
    for (; p + 8 <= s1; p += 8) {
        int idx[8];
#pragma unroll
        for (int j = 0; j < 8; j++) idx[j] = srcs[p + j];
        unsigned u[8];
#pragma unroll
        for (int j = 0; j < 8; j++) u[j] = Pb[(long)idx[j] * 128 + lane];
#pragma unroll
        for (int j = 0; j < 8; j++) {
            float a = blo(u[j]) + qa; a = a > 0.f ? a : 0.f;
            float b = bhi(u[j]) + qb; b = b > 0.f ? b : 0.f;
            sA += a; sB += b; qA += a * a; qB += b * b;
            mxA = fmaxf(mxA, a); mxB = fmaxf(mxB, b);
            mnA = fminf(mnA, a); mnB = fminf(mnB, b);
        }
    }
    if (p + 4 <= s1) {
        int idx[4];
#pragma unroll
        for (int j = 0; j < 4; j++) idx[j] = srcs[p + j];
        unsigned u[4];
#pragma unroll
        for (int j = 0; j < 4; j++) u[j] = Pb[(long)idx[j] * 128 + lane];
#pragma unroll
        for (int j = 0; j < 4; j++) {
            float a = blo(u[j]) + qa; a = a > 0.f ? a : 0.f;
            float b = bhi(u[j]) + qb; b = b > 0.f ? b : 0.f;
            sA += a; sB += b; qA += a * a; qB += b * b;
            mxA = fmaxf(mxA, a); mxB = fmaxf(mxB, b);
            mnA = fminf(mnA, a); mnB = fminf(mnB, b);
        }
        p += 4;
    }
    for (; p < s1; p++) {
        unsigned u = Pb[(long)srcs[p] * 128 + lane];
        float a = blo(u) + qa; a = a > 0.f ? a : 0.f;
        float b = bhi(u) + qb; b = b > 0.f ? b : 0.f;
        sA += a; sB += b; qA += a * a; qB += b * b;
        mxA = fmaxf(mxA, a); mxB = fmaxf(mxB, b);
        mnA = fminf(mnA, a); mnB = fminf(mnB, b);
    }

    float inv = 1.0f / (float)(s1 - s0);   // deg >= 1 guaranteed (self-loops)
    float mA = sA * inv, mB = sB * inv;
    float vA = qA * inv - mA * mA; vA = vA > 0.f ? vA : 0.f;
    float vB = qB * inv - mB * mB; vB = vB > 0.f ? vB : 0.f;
    float stA = sqrtf(vA + EPS_V), stB = sqrtf(vB + EPS_V);

    unsigned* ag = (unsigned*)(aggbf + (long)n * 512);
    ag[lane]       = pk2(mA, mB);
    ag[64 + lane]  = pk2(mxA, mxB);
    ag[128 + lane] = pk2(mnA, mnB);
    ag[192 + lane] = pk2(stA, stB);
}

// ---------------------------------------------------------------- fused post + mix per node
// v7: v4 shape (128-node tile, 32 MFMA/phase) with register-footprint fix:
//   - 2 acc sets (mI + transient tp, VALU fold of amp/att) -> 128 acc floats (was 192)
//     => ~230 combined regs => 2 waves/SIMD, 2 blocks/CU (was 1 wave/SIMD).
//   - 1 barrier per phase: stages issued AFTER the phase barrier (prev-phase LDS reads
//     complete at barrier), B staged 1 ahead (L2-hot), A staged 2 ahead.
//   - h prologue tiles direct global->reg; agg A-frags hoisted to regs once per j.
//   - T5 setprio around MFMA clusters.
__global__ __launch_bounds__(256, 2) void node_kernel(
    const float* __restrict__ h, const short* __restrict__ hbf, const short* __restrict__ aggbf,
    const int* __restrict__ degc, const short* __restrict__ wpostT, const float* __restrict__ bpost,
    const short* __restrict__ wmixT, const float* __restrict__ bmix, float* __restrict__ out)
{
    __shared__ __align__(16) short As[2][8192];   // agg A tiles; reused as hp staging for mix
    __shared__ __align__(16) short Bs[2][8192];
    __shared__ float sAmp[128], sAtt[128];

    const int tid = threadIdx.x;
    const int bn = blockIdx.x * 128;
    const int lane = tid & 63, wv = tid >> 6;
    const int lm = lane & 15, quad = lane >> 4;
    const int r7 = lm & 7;

    if (tid < 128) {
        int n = bn + tid; if (n >= N_NODES) n = N_NODES - 1;
        float d = (float)degc[n];
        float ld = logf(d + 1.0f);
        sAmp[tid] = ld * (1.0f / AVG_D_LOG);
        sAtt[tid] = AVG_D_LOG / ld;
    }
    __syncthreads();   // drains degc load -> vmcnt baseline 0 for exact counted waits

    const float am0 = sAmp[wv * 32 + lm],      at0 = sAtt[wv * 32 + lm];
    const float am1 = sAmp[wv * 32 + 16 + lm], at1 = sAtt[wv * 32 + 16 + lm];

    f32x4 mI[2][8];   // master accumulator (FRESH-initialized at P0)

    // prologue FIFO: h0-frags(4 reg), Bc0(4 lds), h1-frags(4 reg), Aagg0(4 lds)
    bf16x8 hA0[4], hA1[4];
    loadAfr(hA0, hbf, 128, 0, bn, wv, lm, quad);
    SB0();
    stageB_t(Bs[0], wpostT, 1664, 0, wv, lane);
    SB0();
    loadAfr(hA1, hbf, 128, 64, bn, wv, lm, quad);
    SB0();
    stageA_t(As[0], aggbf, 512, 0, bn, wv, lane);      // agg0 (co=0)

    // P0: wait h0+Bc0 (leaves h1+agg0); stage Bc1 -> Bs[1], agg1 -> As[1]; MFMA h0 x c0
    WAIT_BAR(8);
    stageB_t(Bs[1], wpostT, 1664, 64, wv, lane);
    SB0();
    stageA_t(As[1], aggbf, 512, 64, bn, wv, lane);     // agg1 (co=64)
    MFMA_RG(Bs[0], hA0, mI, 1);

    // P1: wait Bc1 (leaves agg1); stage Bid0 -> Bs[0]; MFMA h1 x c1
    WAIT_BAR(4);
    stageB_t(Bs[0], wpostT, 1664, 2 * 64, wv, lane);
    MFMA_RG(Bs[1], hA1, mI, 0);

    // j-loop: phases s0 (id_j), s1 (amp_j), s2 (att_j); 1 barrier per phase.
    // B buffers: s0 reads Bs[j&1], s1 reads Bs[(j&1)^1], s2 reads Bs[j&1].
    for (int j = 0; j < 8; j++) {
        const int pb = j & 1, pn = pb ^ 1;
        const short* Ac = As[pb];
        bf16x8 aR[4];

        // s0: wait 0 (Bid_j staged 1 back, agg_j staged >=2 back, all landed);
        //     stage Bamp_j -> Bs[pn]; hoist A-frags; MFMA id_j -> mI
        WAIT_BAR(0);
        stageB_t(Bs[pn], wpostT, 1664, (10 + j) * 64, wv, lane);
#pragma unroll
        for (int rt = 0; rt < 2; rt++)
#pragma unroll
            for (int ks = 0; ks < 2; ks++)
                aR[rt * 2 + ks] = *(const bf16x8*)&Ac[(wv * 32 + rt * 16 + lm) * 64 + ((ks * 4 + quad) ^ r7) * 8];
        MFMA_RG(Bs[pb], aR, mI, 0);

        // s1: wait 0 (Bamp landed); stage Batt_j -> Bs[pb] then Aagg_{j+1} -> As[pn];
        //     MFMA amp_j -> tp; fold
        WAIT_BAR(0);
        stageB_t(Bs[pb], wpostT, 1664, (18 + j) * 64, wv, lane);
        SB0();
        if (j < 7) {
            int jn = j + 1;
            stageA_t(As[pn], aggbf, 512, (jn >> 1) * 128 + (jn & 1) * 64, bn, wv, lane);
        }
        {
            f32x4 tp[2][8];
            MFMA_RG(Bs[pn], aR, tp, 1);
#pragma unroll
            for (int ct = 0; ct < 8; ct++) {
                mI[0][ct] += am0 * tp[0][ct];
                mI[1][ct] += am1 * tp[1][ct];
            }
        }

        // s2: wait 4 (lands Batt, preserves Aagg_{j+1}) [j=7: wait 0, nothing to preserve];
        //     stage Bid_{j+1} -> Bs[pn] (j=7: Bmix0 -> Bs[0]); MFMA att_j -> tp; fold
        if (j < 7) { WAIT_BAR(4); } else { WAIT_BAR(0); }
        if (j < 7) stageB_t(Bs[pn], wpostT, 1664, (3 + j) * 64, wv, lane);
        else       stageB_t(Bs[pn], wmixT, 128, 0, wv, lane);     // Bmix0 -> Bs[0]
        {
            f32x4 tp[2][8];
            MFMA_RG(Bs[pb], aR, tp, 1);
#pragma unroll
            for (int ct = 0; ct < 8; ct++) {
                mI[0][ct] += at0 * tp[0][ct];
                mI[1][ct] += at1 * tp[1][ct];
            }
        }
    }
    // Bmix0 in flight -> Bs[0]

    // tail: protect Bs[1] (read by att7), then stage Bmix1 -> Bs[1]; combine hp; drain; mix
    BAR_ONLY();
    stageB_t(Bs[1], wmixT, 128, 64, wv, lane);

#pragma unroll
    for (int rt = 0; rt < 2; rt++) {
        const int row = wv * 32 + rt * 16 + lm;
#pragma unroll
        for (int ct = 0; ct < 8; ct++) {
            float4 bv = *(const float4*)(bpost + ct * 16 + quad * 4);
            float v0 = mI[rt][ct][0] + bv.x; v0 = v0 > 0.f ? v0 : 0.f;
            float v1 = mI[rt][ct][1] + bv.y; v1 = v1 > 0.f ? v1 : 0.f;
            float v2 = mI[rt][ct][2] + bv.z; v2 = v2 > 0.f ? v2 : 0.f;
            float v3 = mI[rt][ct][3] + bv.w; v3 = v3 > 0.f ? v3 : 0.f;
            int2 pkd; pkd.x = (int)pk2(v0, v1); pkd.y = (int)pk2(v2, v3);
            const int cb = (ct & 3) * 32 + quad * 8;           // byte off within 128B row
            const int sb = ((((cb >> 4) ^ r7) << 4) | (cb & 15));
            *(int2*)((char*)As[ct >> 2] + row * 128 + sb) = pkd;
        }
    }
    __syncthreads();   // full drain: mix loads (vmcnt) + hp writes (lgkm)

    // ---- mix GEMM: K=128, hp in As[0..1], Wmix in Bs[0..1]
    f32x4 accO[2][8];
#pragma unroll
    for (int a = 0; a < 2; a++)
#pragma unroll
        for (int b = 0; b < 8; b++) accO[a][b] = (f32x4){0.f, 0.f, 0.f, 0.f};
#pragma unroll
    for (int kc = 0; kc < 2; kc++) {
        MFMA_ITER(As[kc], Bs[kc], accO);
    }

    // epilogue: out = h + leaky_relu(accO + b_mix)
#pragma unroll
    for (int rt = 0; rt < 2; rt++) {
        int row = wv * 32 + rt * 16 + lm;
        int n = bn + row;
        if (n >= N_NODES) continue;
#pragma unroll
        for (int ct = 0; ct < 8; ct++) {
            int col = ct * 16 + quad * 4;
            float4 bv = *(const float4*)(bmix + col);
            float4 hv = *(const float4*)(h + (long)n * 128 + col);
            float4 o;
            float v0 = accO[rt][ct][0] + bv.x; v0 = v0 > 0.f ? v0 : 0.01f * v0; o.x = hv.x + v0;
            float v1 = accO[rt][ct][1] + bv.y; v1 = v1 > 0.f ? v1 : 0.01f * v1; o.y = hv.y + v1;
            float v2 = accO[rt][ct][2] + bv.z; v2 = v2 > 0.f ? v2 : 0.01f * v2; o.z = hv.z + v2;
            float v3 = accO[rt][ct][3] + bv.w; v3 = v3 > 0.f ? v3 : 0.01f * v3; o.w = hv.w + v3;
            *(float4*)(out + (long)n * 128 + col) = o;
        }
    }
}

extern "C" void kernel_launch(void* const* d_in, const int* in_sizes, int n_in,
                              void* d_out, int out_size, void* d_ws, size_t ws_size,
                              hipStream_t stream) {
    const float* h     = (const float*)d_in[0];
    const int*   esrc  = (const int*)d_in[1];
    const int*   edst  = (const int*)d_in[2];
    const float* Wpre  = (const float*)d_in[3];
    const float* bpre  = (const float*)d_in[4];
    const float* Wpost = (const float*)d_in[5];
    const float* bpost = (const float*)d_in[6];
    const float* Wmix  = (const float*)d_in[7];
    const float* bmix  = (const float*)d_in[8];
    float* out = (float*)d_out;
    char* ws = (char*)d_ws;

    short* PQ     = (short*)(ws + PQ_B);
    short* aggbf  = (short*)(ws + AGG_B);
    short* hbf    = (short*)(ws + HBF_B);
    short* wpreT2 = (short*)(ws + WPRET2_B);
    short* wpostT = (short*)(ws + WPOSTT_B);
    short* wmixT  = (short*)(ws + WMIXT_B);
    int*   degc   = (int*)(ws + DEGC_B);
    int*   off    = (int*)(ws + OFF_B);
    int*   cursor = (int*)(ws + CUR_B);
    int*   srcs   = (int*)(ws + SRCS_B);
    int*   gcnt   = (int*)(ws + GCNT_B);

    prep_kernel<<<PREP_BLOCKS, 256, 0, stream>>>(h, Wpre, Wpost, Wmix, hbf, wpreT2, wpostT, wmixT, degc, cursor, gcnt);
    hist_kernel<<<(N_EDGES + 255) / 256, 256, 0, stream>>>(edst, degc);
    alloc_kernel<<<(N_NODES + 255) / 256, 256, 0, stream>>>(degc, off, gcnt);
    scatter_kernel<<<(N_EDGES + 255) / 256, 256, 0, stream>>>(esrc, edst, off, cursor, srcs);
    gemm_pq_kernel<<<((N_NODES + 127) / 128) * 2, 256, 0, stream>>>(hbf, wpreT2, bpre, PQ);
    edgestats_kernel<<<N_NODES / 4, 256, 0, stream>>>(PQ, srcs, off, degc, aggbf);
    node_kernel<<<(N_NODES + 127) / 128, 256, 0, stream>>>(h, hbf, aggbf, degc, wpostT, bpost, wmixT, bmix, out);
}